// Round 8
// baseline (300.422 us; speedup 1.0000x reference)
//
#include <hip/hip_runtime.h>

#define EPS 1e-5f
#define NB 8
#define NC 64
#define NH 224
#define NW 224
#define PLANE (NH*NW)            // 50176
#define NPIX (NB*PLANE)          // 401408
#define OUT_ELEMS (NB*NC*PLANE)  // 25690112

typedef __attribute__((ext_vector_type(8)))  short short8;
typedef __attribute__((ext_vector_type(16))) float floatx16;
typedef unsigned int u32;

// bf16 helpers (RNE)
__device__ __forceinline__ unsigned short f2bf(float f) {
    unsigned u = __float_as_uint(f);
    unsigned r = (u + 0x7fffu + ((u >> 16) & 1u)) >> 16;
    return (unsigned short)r;
}
__device__ __forceinline__ float bf2f(unsigned short s) {
    return __uint_as_float(((unsigned)s) << 16);
}

// ws layout (bytes):
//   [0, 147456)    wt: [tap 9][chunk 4] slabs of 4096B:
//                  { wh[oc 64][icl 16] 2048B | wl[oc 64][icl 16] 2048B }
//   [147456,+512)  stats: 64 sum + 64 sumsq floats
#define WT_BYTES (9*4*4096)

// ---------------------------------------------------------------------------
// KW: merge 1x1 into 3x3 (Wm[o][i][tap] = sum_k w1[o][k]*wb[k][i][tap]);
// hi/lo bf16 split of weights. LDS-staged. Zeroes stats.
__global__ __launch_bounds__(256)
void kw_merge(const float* __restrict__ w_bin,
              const float* __restrict__ w1x1,
              unsigned char* __restrict__ ws)
{
    __shared__ float w1[4096];   // [oc][k]
    __shared__ float wb[576];    // [k][tap] for this ic
    const int ic  = blockIdx.x;
    const int tid = threadIdx.x;
    for (int i = tid; i < 4096; i += 256) w1[i] = w1x1[i];
    for (int i = tid; i < 576; i += 256) {
        const int k = i / 9, tap = i % 9;
        wb[i] = w_bin[(k*64 + ic)*9 + tap];
    }
    __syncthreads();
    for (int i = tid; i < 576; i += 256) {
        const int oc = i / 9, tap = i % 9;
        float acc = 0.f;
#pragma unroll
        for (int k = 0; k < 64; ++k) acc += w1[oc*64 + k] * wb[k*9 + tap];
        const unsigned short wh = f2bf(acc);
        const unsigned short wl = f2bf(acc - bf2f(wh));
        const int base = (tap*4 + (ic >> 4)) * 4096;
        const int sb   = oc*32 + (ic & 15)*2;
        *(unsigned short*)(ws + base + sb)        = wh;
        *(unsigned short*)(ws + base + 2048 + sb) = wl;
    }
    if (ic == 0 && tid < 128)
        ((float*)(ws + WT_BYTES))[tid] = 0.f;
}

// ---------------------------------------------------------------------------
// K1: merged conv via bf16 MFMA, 2 products (wh*xh + wl*xh).
// Block = 2 rows x 128 cols x 64 oc; 4 waves = (row, colhalf);
// wave tile = 1 row x 64 cols x 64 oc, acc[2 mf][2 nf] (64 AGPR).
// Fused per-channel sum/sumsq. LDS x slab [hh 2][rr 4][cc 130] x 16B.
#define XS_W  130
#define XS_SLAB (2*4*XS_W*16)   // 16640 B

__global__ __launch_bounds__(256, 4)
void k1_conv(const float* __restrict__ x,
             const unsigned char* __restrict__ wt,
             const float* __restrict__ b1x1,
             float* __restrict__ y,
             float* __restrict__ stats)
{
    __shared__ char smem[XS_SLAB];
    const int tid  = threadIdx.x;
    const int w    = tid >> 6;
    const int wrow = w & 1;            // wave's row within block
    const int ch   = w >> 1;           // wave's col-half (64 cols)
    const int lane = tid & 63;
    const int l31  = lane & 31;
    const int h    = lane >> 5;        // k-half (also oc +4h in C/D rows)
    const int c0   = blockIdx.x * 96;  // col strips [0,128) and [96,224)
    const int r0   = blockIdx.y * 2;
    const int b    = blockIdx.z;

    floatx16 c[2][2];
#pragma unroll
    for (int mf = 0; mf < 2; ++mf)
#pragma unroll
        for (int r = 0; r < 16; ++r) {
            const int oc = mf*32 + (r & 3) + 8*(r >> 2) + 4*h;
            const float bias = b1x1[oc];
            c[mf][0][r] = bias;
            c[mf][1][r] = bias;
        }

    const unsigned alane = (unsigned)(l31*32 + (h << 4));
    auto ldA = [&](int slab, int part) -> short8 {
        return *(const short8*)(wt + (size_t)slab*4096u + (unsigned)part + alane);
    };
    short8 ah0 = ldA(0, 0), ah1 = ldA(0, 1024), al0 = ldA(0, 2048), al1 = ldA(0, 3072);

#pragma unroll 1
    for (int chunk = 0; chunk < 4; ++chunk) {
        __syncthreads();   // previous chunk's LDS reads complete
        // ---- stage x chunk: branchless (clamped addr + mask), pipelined ----
        const float* xc = x + (size_t)(b*NC + chunk*16)*PLANE;
        for (int i = tid; i < 2*4*XS_W; i += 256) {      // 1040 granules
            const int cc = i % XS_W;
            const int t  = i / XS_W;       // hh*4 + rr
            const int rr = t & 3;
            const int hh = t >> 2;
            const int gr = r0 - 1 + rr;
            const int gc = c0 - 1 + cc;
            const bool valid = ((unsigned)gr < (unsigned)NH) && ((unsigned)gc < (unsigned)NW);
            const int grc = valid ? gr : 0;
            const int gcc = valid ? gc : 0;
            const unsigned short msk = valid ? 0xFFFFu : 0u;
            const float* p = xc + (size_t)(hh*8)*PLANE + (size_t)grc*NW + gcc;
            short8 sv;
#pragma unroll
            for (int e = 0; e < 8; ++e)
                sv[e] = (short)(f2bf(p[(size_t)e*PLANE]) & msk);
            *(short8*)(smem + (size_t)(t*XS_W + cc)*16u) = sv;
        }
        __syncthreads();   // xs ready

#pragma unroll 1
        for (int tap = 0; tap < 9; ++tap) {
            // prefetch next tap's A fragments (global->reg, L2-hot)
            int ntap = tap + 1, nchunk = chunk;
            if (ntap == 9) { ntap = 0; nchunk = chunk + 1; }
            short8 nh0 = ah0, nh1 = ah1, nl0 = al0, nl1 = al1;
            if (nchunk < 4) {
                const int ns = ntap*4 + nchunk;
                nh0 = ldA(ns, 0);    nh1 = ldA(ns, 1024);
                nl0 = ldA(ns, 2048); nl1 = ldA(ns, 3072);
            }

            const int dy = tap / 3, dx = tap - dy*3;
            const unsigned bbase =
                ((unsigned)(h*4 + wrow + dy)*XS_W + (unsigned)(dx + ch*64 + l31))*16u;
#pragma unroll
            for (int nf = 0; nf < 2; ++nf) {
                short8 bb = *(const short8*)(smem + bbase + (unsigned)nf*512u);
                c[0][nf] = __builtin_amdgcn_mfma_f32_32x32x16_bf16(ah0, bb, c[0][nf], 0, 0, 0);
                c[1][nf] = __builtin_amdgcn_mfma_f32_32x32x16_bf16(ah1, bb, c[1][nf], 0, 0, 0);
                c[0][nf] = __builtin_amdgcn_mfma_f32_32x32x16_bf16(al0, bb, c[0][nf], 0, 0, 0);
                c[1][nf] = __builtin_amdgcn_mfma_f32_32x32x16_bf16(al1, bb, c[1][nf], 0, 0, 0);
            }
            ah0 = nh0; ah1 = nh1; al0 = nl0; al1 = nl1;
        }
    }

    // ---- epilogue: store y ----
    const int row = r0 + wrow;
#pragma unroll
    for (int mf = 0; mf < 2; ++mf)
#pragma unroll
        for (int r = 0; r < 16; ++r) {
            const int oc = mf*32 + (r & 3) + 8*(r >> 2) + 4*h;
            float* yp = y + ((size_t)(b*NC + oc)*NH + row)*NW + c0 + ch*64 + l31;
            yp[0]  = c[mf][0][r];
            yp[32] = c[mf][1][r];
        }

    // ---- fused stats: per-channel sum/sumsq (each pixel counted once) ----
    // strip B (c0!=0) duplicates block-cols <32 (global 96..127) -> mask ch0/nf0.
    const float m0 = (c0 != 0 && ch == 0) ? 0.f : 1.f;
    __syncthreads();                   // all MFMA LDS reads done; reuse smem
    float* sst = (float*)smem;         // [wave 4][128]: sum[oc] | sq[oc]
#pragma unroll
    for (int mf = 0; mf < 2; ++mf)
#pragma unroll
        for (int r = 0; r < 16; ++r) {
            const float v0 = c[mf][0][r], v1 = c[mf][1][r];
            float p = m0*v0 + v1;
            float q = m0*v0*v0 + v1*v1;
#pragma unroll
            for (int off = 1; off < 32; off <<= 1) {     // reduce within 32-lane half
                p += __shfl_xor(p, off);
                q += __shfl_xor(q, off);
            }
            if (l31 == 0) {
                const int oc = mf*32 + (r & 3) + 8*(r >> 2) + 4*h;
                sst[w*128 + oc]      = p;
                sst[w*128 + 64 + oc] = q;
            }
        }
    __syncthreads();
    if (tid < 128) {
        const float s = sst[tid] + sst[128 + tid] + sst[256 + tid] + sst[384 + tid];
        atomicAdd(&stats[tid], s);
    }
}

// ---------------------------------------------------------------------------
// K3: BN (batch stats) + leaky + clamp (== clamp(t,0,255)).
// Block = 1/4 of one (b,c) plane -> uniform scale/shift; 2048 blocks (8/CU).
__global__ __launch_bounds__(256)
void k3_bn(float* __restrict__ y, const float* __restrict__ stats,
           const float* __restrict__ gamma, const float* __restrict__ beta)
{
    const int seg = blockIdx.x;        // 0..3
    const int cch = blockIdx.y;        // 0..63
    const int b   = blockIdx.z;        // 0..7
    const float inv_n = 1.f / (float)NPIX;
    const float mean = stats[cch] * inv_n;
    const float var  = stats[64 + cch] * inv_n - mean*mean;
    const float sc   = gamma[cch] * rsqrtf(var + EPS);
    const float sh   = beta[cch] - mean*sc;
    float4* p = (float4*)(y + (size_t)(b*NC + cch)*PLANE) + seg*(PLANE/16);
    for (int i = threadIdx.x; i < PLANE/16; i += 256) {
        float4 v = p[i];
        v.x = fminf(fmaxf(v.x*sc + sh, 0.f), 255.f);
        v.y = fminf(fmaxf(v.y*sc + sh, 0.f), 255.f);
        v.z = fminf(fmaxf(v.z*sc + sh, 0.f), 255.f);
        v.w = fminf(fmaxf(v.w*sc + sh, 0.f), 255.f);
        p[i] = v;
    }
}

// ---------------------------------------------------------------------------
extern "C" void kernel_launch(void* const* d_in, const int* in_sizes, int n_in,
                              void* d_out, int out_size, void* d_ws, size_t ws_size,
                              hipStream_t stream)
{
    const float* x     = (const float*)d_in[0];
    const float* w_bin = (const float*)d_in[1];
    const float* w1x1  = (const float*)d_in[2];
    const float* b1x1  = (const float*)d_in[3];
    const float* gamma = (const float*)d_in[4];
    const float* beta  = (const float*)d_in[5];
    float* out = (float*)d_out;
    unsigned char* wt = (unsigned char*)d_ws;
    float* stats = (float*)((char*)d_ws + WT_BYTES);

    kw_merge<<<64, 256, 0, stream>>>(w_bin, w1x1, wt);
    k1_conv<<<dim3(2, 112, NB), 256, 0, stream>>>(x, wt, b1x1, out, stats);
    k3_bn<<<dim3(4, 64, NB), 256, 0, stream>>>(out, stats, gamma, beta);
}